// Round 1
// baseline (665.980 us; speedup 1.0000x reference)
//
#include <hip/hip_runtime.h>
#include <hip/hip_bf16.h>
#include <stdint.h>

typedef __bf16 bf16x8 __attribute__((ext_vector_type(8)));
typedef float f32x4 __attribute__((ext_vector_type(4)));

#define NH 16
#define NKV 4
#define HD 128
#define HQ (NH*HD)    // 2048
#define HKV (NKV*HD)  // 512

__device__ __forceinline__ void gl_lds16(const void* g, void* l) {
  __builtin_amdgcn_global_load_lds(
      (const __attribute__((address_space(1))) void*)g,
      (__attribute__((address_space(3))) void*)l, 16, 0, 0);
}

// ---------------- fp32 -> bf16 cast, 4 elems/thread ----------------
__global__ void k_cast_bf16(const float* __restrict__ in,
                            __hip_bfloat16* __restrict__ out, int n4) {
  int i = blockIdx.x * blockDim.x + threadIdx.x;
  if (i >= n4) return;
  float4 v = reinterpret_cast<const float4*>(in)[i];
  union { __hip_bfloat16 b[4]; ushort4 u; } o;
  o.b[0] = __float2bfloat16(v.x); o.b[1] = __float2bfloat16(v.y);
  o.b[2] = __float2bfloat16(v.z); o.b[3] = __float2bfloat16(v.w);
  reinterpret_cast<ushort4*>(out)[i] = o.u;
}

// ---------------- RoPE cos/sin table: [ntok][64] each ----------------
__global__ void k_rope_table(const int* __restrict__ pid,
                             float* __restrict__ cosT, float* __restrict__ sinT,
                             int ntok) {
  int idx = blockIdx.x * blockDim.x + threadIdx.x;
  if (idx >= ntok * 64) return;
  int tok = idx >> 6, i = idx & 63;
  // sniff int64 vs int32 position_ids (little-endian): arange -> pid32[1]==1 iff int32
  bool is64 = (pid[1] == 0);
  int pos = is64 ? pid[2 * tok] : pid[tok];
  // inv_freq = 10000^(-i/64) = exp(-i/64 * ln 10000)
  float f = (float)pos * __expf(-(float)i * (9.210340371976184f / 64.0f));
  cosT[idx] = cosf(f);
  sinT[idx] = sinf(f);
}

// ---------------- RoPE apply in-place on bf16 [ntok][nheads*128] ----------------
__global__ void k_rope_apply(__hip_bfloat16* __restrict__ X,
                             const float* __restrict__ cosT,
                             const float* __restrict__ sinT,
                             int nheads, int ntok) {
  int idx = blockIdx.x * blockDim.x + threadIdx.x;
  if (idx >= ntok * nheads * 64) return;
  int i = idx & 63;
  int hh = (idx >> 6) % nheads;
  int tok = idx / (nheads * 64);
  size_t base = (size_t)tok * nheads * 128 + hh * 128;
  float c = cosT[tok * 64 + i], s = sinT[tok * 64 + i];
  float x0 = __bfloat162float(X[base + i]);
  float x1 = __bfloat162float(X[base + 64 + i]);
  X[base + i]      = __float2bfloat16(x0 * c - x1 * s);
  X[base + 64 + i] = __float2bfloat16(x1 * c + x0 * s);
}

// ---------------- V transpose: [b*S+s][kvh*128+d] -> [(b*4+kvh)*128+d][s] ----------------
__global__ void k_transpose_v(const __hip_bfloat16* __restrict__ V,
                              __hip_bfloat16* __restrict__ Vt, int S) {
  __shared__ __hip_bfloat16 tile[32][33];
  int bkv = blockIdx.z;           // b*4+kvh
  int b = bkv >> 2, kvh = bkv & 3;
  int s0 = blockIdx.x * 32, d0 = blockIdx.y * 32;
  int tx = threadIdx.x, ty = threadIdx.y;  // (32,8)
  for (int i = 0; i < 32; i += 8)
    tile[ty + i][tx] = V[((size_t)(b * S) + s0 + ty + i) * HKV + kvh * 128 + d0 + tx];
  __syncthreads();
  for (int i = 0; i < 32; i += 8)
    Vt[((size_t)bkv * 128 + d0 + ty + i) * S + s0 + tx] = tile[tx][ty + i];
}

// ---------------- bf16 GEMM: C[M,N] = A[M,K] * B[N,K]^T ----------------
template <bool OUT_F32>
__global__ __launch_bounds__(256, 2) void k_gemm_bt(
    const __hip_bfloat16* __restrict__ A, const __hip_bfloat16* __restrict__ B,
    void* __restrict__ Cv, int M, int N, int K) {
  __shared__ __hip_bfloat16 As[128 * 32];
  __shared__ __hip_bfloat16 Bs[128 * 32];
  const int t = threadIdx.x;
  const int w = t >> 6, l = t & 63;
  const int lr = l & 15, lg = l >> 4;
  const int wr = w >> 1, wc = w & 1;
  const int bm = blockIdx.x, bn = blockIdx.y;

  const __hip_bfloat16* ga = A + (size_t)(bm * 128 + (t >> 2)) * K + (t & 3) * 8;
  const __hip_bfloat16* gb = B + (size_t)(bn * 128 + (t >> 2)) * K + (t & 3) * 8;
  __hip_bfloat16* la = As + w * 512;
  __hip_bfloat16* lb = Bs + w * 512;

  f32x4 acc[4][4] = {};

  const int nk = K >> 5;
  for (int kb = 0; kb < nk; ++kb) {
    gl_lds16(ga, la);
    gl_lds16(ga + (size_t)64 * K, la + 2048);
    gl_lds16(gb, lb);
    gl_lds16(gb + (size_t)64 * K, lb + 2048);
    ga += 32; gb += 32;
    asm volatile("s_waitcnt vmcnt(0)" ::: "memory");
    __syncthreads();
    bf16x8 af[4], bfr[4];
#pragma unroll
    for (int m = 0; m < 4; ++m)
      af[m] = *reinterpret_cast<const bf16x8*>(&As[(wr * 64 + m * 16 + lr) * 32 + lg * 8]);
#pragma unroll
    for (int n = 0; n < 4; ++n)
      bfr[n] = *reinterpret_cast<const bf16x8*>(&Bs[(wc * 64 + n * 16 + lr) * 32 + lg * 8]);
#pragma unroll
    for (int m = 0; m < 4; ++m)
#pragma unroll
      for (int n = 0; n < 4; ++n)
        acc[m][n] = __builtin_amdgcn_mfma_f32_16x16x32_bf16(af[m], bfr[n], acc[m][n], 0, 0, 0);
    __syncthreads();
  }

  const int row0 = bm * 128 + wr * 64, col0 = bn * 128 + wc * 64;
#pragma unroll
  for (int m = 0; m < 4; ++m)
#pragma unroll
    for (int n = 0; n < 4; ++n)
#pragma unroll
      for (int r = 0; r < 4; ++r) {
        int row = row0 + m * 16 + lg * 4 + r;
        int col = col0 + n * 16 + lr;
        if (OUT_F32)
          ((float*)Cv)[(size_t)row * N + col] = acc[m][n][r];
        else
          ((__hip_bfloat16*)Cv)[(size_t)row * N + col] = __float2bfloat16(acc[m][n][r]);
      }
}

// ---------------- causal GQA flash attention ----------------
// Q:[B*S][2048] K:[B*S][512] Vt:[(b*4+kvh)*128+d][S] ctx:[B*S][2048]
__global__ __launch_bounds__(256, 2) void k_attn(
    const __hip_bfloat16* __restrict__ Q, const __hip_bfloat16* __restrict__ Kb,
    const __hip_bfloat16* __restrict__ Vt, __hip_bfloat16* __restrict__ ctx, int S) {
  __shared__ __hip_bfloat16 Plds[4][16][72];  // per-wave P tile, padded
  const int qt = blockIdx.x;
  const int bh = blockIdx.y;
  const int b = bh >> 4, h = bh & 15, kvh = h >> 2;
  const int t = threadIdx.x, w = t >> 6, l = t & 63;
  const int lr = l & 15, lg = l >> 4;
  const int q0 = qt * 64 + w * 16;  // within-sequence q row base for this wave
  const float scale = 0.08838834764831845f;  // 1/sqrt(128)

  const __hip_bfloat16* Qp = Q + ((size_t)(b * S) + q0) * HQ + h * 128;
  bf16x8 aq[4];
#pragma unroll
  for (int kk = 0; kk < 4; ++kk)
    aq[kk] = *reinterpret_cast<const bf16x8*>(&Qp[(size_t)lr * HQ + kk * 32 + lg * 8]);

  const __hip_bfloat16* Kbase = Kb + (size_t)(b * S) * HKV + kvh * 128;
  const __hip_bfloat16* Vtb = Vt + ((size_t)(b * NKV + kvh) * 128) * S;

  f32x4 oacc[8] = {};
  float m_i[4], l_i[4];
#pragma unroll
  for (int r = 0; r < 4; ++r) { m_i[r] = -3.0e38f; l_i[r] = 0.0f; }

  const int ntiles = qt + 1;
  for (int tkv = 0; tkv < ntiles; ++tkv) {
    const int kv0 = tkv * 64;
    const bool diag = (tkv == qt);
    float smax[4];
#pragma unroll
    for (int r = 0; r < 4; ++r) smax[r] = -3.0e38f;
    f32x4 sreg[4];
#pragma unroll
    for (int ks = 0; ks < 4; ++ks) {
      f32x4 s = {0.f, 0.f, 0.f, 0.f};
      const __hip_bfloat16* Kp = Kbase + (size_t)(kv0 + ks * 16 + lr) * HKV;
#pragma unroll
      for (int kk = 0; kk < 4; ++kk)
        s = __builtin_amdgcn_mfma_f32_16x16x32_bf16(
            aq[kk], *reinterpret_cast<const bf16x8*>(&Kp[kk * 32 + lg * 8]), s, 0, 0, 0);
      const int kvcol = kv0 + ks * 16 + lr;
#pragma unroll
      for (int r = 0; r < 4; ++r) {
        float v = s[r] * scale;
        if (diag && kvcol > q0 + lg * 4 + r) v = -1.0e30f;
        s[r] = v;
        smax[r] = fmaxf(smax[r], v);
      }
      sreg[ks] = s;
    }
    // row-max across the 16-lane col group
#pragma unroll
    for (int off = 1; off < 16; off <<= 1)
#pragma unroll
      for (int r = 0; r < 4; ++r) smax[r] = fmaxf(smax[r], __shfl_xor(smax[r], off, 64));

    float fac[4];
#pragma unroll
    for (int r = 0; r < 4; ++r) {
      float mn = fmaxf(m_i[r], smax[r]);
      fac[r] = __expf(m_i[r] - mn);
      m_i[r] = mn;
      l_i[r] *= fac[r];
    }
#pragma unroll
    for (int dt = 0; dt < 8; ++dt)
#pragma unroll
      for (int r = 0; r < 4; ++r) oacc[dt][r] *= fac[r];

    float rs[4] = {0.f, 0.f, 0.f, 0.f};
#pragma unroll
    for (int ks = 0; ks < 4; ++ks)
#pragma unroll
      for (int r = 0; r < 4; ++r) {
        float p = __expf(sreg[ks][r] - m_i[r]);
        rs[r] += p;
        Plds[w][lg * 4 + r][ks * 16 + lr] = __float2bfloat16(p);
      }
#pragma unroll
    for (int off = 1; off < 16; off <<= 1)
#pragma unroll
      for (int r = 0; r < 4; ++r) rs[r] += __shfl_xor(rs[r], off, 64);
#pragma unroll
    for (int r = 0; r < 4; ++r) l_i[r] += rs[r];

    asm volatile("s_waitcnt lgkmcnt(0)" ::: "memory");
    __builtin_amdgcn_sched_barrier(0);

    bf16x8 pa[2];
    pa[0] = *reinterpret_cast<const bf16x8*>(&Plds[w][lr][lg * 8]);
    pa[1] = *reinterpret_cast<const bf16x8*>(&Plds[w][lr][32 + lg * 8]);
#pragma unroll
    for (int dt = 0; dt < 8; ++dt) {
      const __hip_bfloat16* Vp = Vtb + (size_t)(dt * 16 + lr) * S + kv0;
      f32x4 o = oacc[dt];
      o = __builtin_amdgcn_mfma_f32_16x16x32_bf16(
          pa[0], *reinterpret_cast<const bf16x8*>(&Vp[lg * 8]), o, 0, 0, 0);
      o = __builtin_amdgcn_mfma_f32_16x16x32_bf16(
          pa[1], *reinterpret_cast<const bf16x8*>(&Vp[32 + lg * 8]), o, 0, 0, 0);
      oacc[dt] = o;
    }
  }

  float inv_l[4];
#pragma unroll
  for (int r = 0; r < 4; ++r) inv_l[r] = 1.0f / l_i[r];
  __hip_bfloat16* Cp = ctx + ((size_t)(b * S) + q0) * HQ + h * 128;
#pragma unroll
  for (int dt = 0; dt < 8; ++dt)
#pragma unroll
    for (int r = 0; r < 4; ++r)
      Cp[(size_t)(lg * 4 + r) * HQ + dt * 16 + lr] =
          __float2bfloat16(oacc[dt][r] * inv_l[r]);
}

// ---------------------------------------------------------------
extern "C" void kernel_launch(void* const* d_in, const int* in_sizes, int n_in,
                              void* d_out, int out_size, void* d_ws, size_t ws_size,
                              hipStream_t stream) {
  const int B = 2, S = 2048, H = 2048;
  const int M = B * S;  // 4096 tokens

  const float* hs = (const float*)d_in[0];
  const float* wq = (const float*)d_in[1];
  const float* wk = (const float*)d_in[2];
  const float* wv = (const float*)d_in[3];
  const float* wo = (const float*)d_in[4];
  const int* pid = (const int*)d_in[6];

  char* p = (char*)d_ws;
  auto carve = [&](size_t bytes) {
    void* r = (void*)p;
    p += (bytes + 255) & ~(size_t)255;
    return r;
  };
  __hip_bfloat16* Xb  = (__hip_bfloat16*)carve((size_t)M * H * 2);
  __hip_bfloat16* Wqb = (__hip_bfloat16*)carve((size_t)HQ * H * 2);
  __hip_bfloat16* Wkb = (__hip_bfloat16*)carve((size_t)HKV * H * 2);
  __hip_bfloat16* Wvb = (__hip_bfloat16*)carve((size_t)HKV * H * 2);
  __hip_bfloat16* Wob = (__hip_bfloat16*)carve((size_t)H * HQ * 2);
  __hip_bfloat16* Qb  = (__hip_bfloat16*)carve((size_t)M * HQ * 2);
  __hip_bfloat16* Kb  = (__hip_bfloat16*)carve((size_t)M * HKV * 2);
  __hip_bfloat16* Vb  = (__hip_bfloat16*)carve((size_t)M * HKV * 2);
  __hip_bfloat16* Vtb = (__hip_bfloat16*)carve((size_t)M * HKV * 2);
  __hip_bfloat16* Ctx = (__hip_bfloat16*)carve((size_t)M * HQ * 2);
  float* cosT = (float*)carve((size_t)M * 64 * 4);
  float* sinT = (float*)carve((size_t)M * 64 * 4);

  // casts
  {
    int n4 = M * H / 4;
    k_cast_bf16<<<(n4 + 255) / 256, 256, 0, stream>>>(hs, Xb, n4);
    n4 = HQ * H / 4;
    k_cast_bf16<<<(n4 + 255) / 256, 256, 0, stream>>>(wq, Wqb, n4);
    n4 = HKV * H / 4;
    k_cast_bf16<<<(n4 + 255) / 256, 256, 0, stream>>>(wk, Wkb, n4);
    k_cast_bf16<<<(n4 + 255) / 256, 256, 0, stream>>>(wv, Wvb, n4);
    n4 = H * HQ / 4;
    k_cast_bf16<<<(n4 + 255) / 256, 256, 0, stream>>>(wo, Wob, n4);
  }

  // RoPE table
  k_rope_table<<<(M * 64 + 255) / 256, 256, 0, stream>>>(pid, cosT, sinT, M);

  // projections
  k_gemm_bt<false><<<dim3(M / 128, HQ / 128), 256, 0, stream>>>(Xb, Wqb, Qb, M, HQ, H);
  k_gemm_bt<false><<<dim3(M / 128, HKV / 128), 256, 0, stream>>>(Xb, Wkb, Kb, M, HKV, H);
  k_gemm_bt<false><<<dim3(M / 128, HKV / 128), 256, 0, stream>>>(Xb, Wvb, Vb, M, HKV, H);

  // RoPE on Q and K
  k_rope_apply<<<(M * NH * 64 + 255) / 256, 256, 0, stream>>>(Qb, cosT, sinT, NH, M);
  k_rope_apply<<<(M * NKV * 64 + 255) / 256, 256, 0, stream>>>(Kb, cosT, sinT, NKV, M);

  // V transpose
  k_transpose_v<<<dim3(S / 32, 128 / 32, B * NKV), dim3(32, 8), 0, stream>>>(Vb, Vtb, S);

  // attention
  k_attn<<<dim3(S / 64, B * NH), 256, 0, stream>>>(Qb, Kb, Vtb, Ctx, S);

  // output projection (fp32 out)
  k_gemm_bt<true><<<dim3(M / 128, H / 128), 256, 0, stream>>>(Ctx, Wob, (float*)d_out, M, H, HQ);
}

// Round 2
// 349.106 us; speedup vs baseline: 1.9077x; 1.9077x over previous
//
#include <hip/hip_runtime.h>
#include <hip/hip_bf16.h>
#include <stdint.h>

typedef __bf16 bf16x8 __attribute__((ext_vector_type(8)));
typedef float f32x4 __attribute__((ext_vector_type(4)));

#define NH 16
#define NKV 4
#define HD 128
#define HQ (NH*HD)    // 2048
#define HKV (NKV*HD)  // 512
#define KVB 64

__device__ __forceinline__ void gl_lds16(const void* g, void* l) {
  __builtin_amdgcn_global_load_lds(
      (const __attribute__((address_space(1))) void*)g,
      (__attribute__((address_space(3))) void*)l, 16, 0, 0);
}

// ---------------- fp32 -> bf16 cast, 4 elems/thread ----------------
__global__ void k_cast_bf16(const float* __restrict__ in,
                            __hip_bfloat16* __restrict__ out, int n4) {
  int i = blockIdx.x * blockDim.x + threadIdx.x;
  if (i >= n4) return;
  float4 v = reinterpret_cast<const float4*>(in)[i];
  union { __hip_bfloat16 b[4]; ushort4 u; } o;
  o.b[0] = __float2bfloat16(v.x); o.b[1] = __float2bfloat16(v.y);
  o.b[2] = __float2bfloat16(v.z); o.b[3] = __float2bfloat16(v.w);
  reinterpret_cast<ushort4*>(out)[i] = o.u;
}

// ---------------- RoPE cos/sin table: [ntok][64] each ----------------
__global__ void k_rope_table(const int* __restrict__ pid,
                             float* __restrict__ cosT, float* __restrict__ sinT,
                             int ntok) {
  int idx = blockIdx.x * blockDim.x + threadIdx.x;
  if (idx >= ntok * 64) return;
  int tok = idx >> 6, i = idx & 63;
  bool is64 = (pid[1] == 0);
  int pos = is64 ? pid[2 * tok] : pid[tok];
  float f = (float)pos * __expf(-(float)i * (9.210340371976184f / 64.0f));
  cosT[idx] = cosf(f);
  sinT[idx] = sinf(f);
}

// ---------------- RoPE apply in-place on bf16 [ntok][nheads*128] ----------------
__global__ void k_rope_apply(__hip_bfloat16* __restrict__ X,
                             const float* __restrict__ cosT,
                             const float* __restrict__ sinT,
                             int nheads, int ntok) {
  int idx = blockIdx.x * blockDim.x + threadIdx.x;
  if (idx >= ntok * nheads * 64) return;
  int i = idx & 63;
  int hh = (idx >> 6) % nheads;
  int tok = idx / (nheads * 64);
  size_t base = (size_t)tok * nheads * 128 + hh * 128;
  float c = cosT[tok * 64 + i], s = sinT[tok * 64 + i];
  float x0 = __bfloat162float(X[base + i]);
  float x1 = __bfloat162float(X[base + 64 + i]);
  X[base + i]      = __float2bfloat16(x0 * c - x1 * s);
  X[base + 64 + i] = __float2bfloat16(x1 * c + x0 * s);
}

// ---------------- V transpose: [b*S+s][kvh*128+d] -> [(b*4+kvh)*128+d][s] ----------------
__global__ void k_transpose_v(const __hip_bfloat16* __restrict__ V,
                              __hip_bfloat16* __restrict__ Vt, int S) {
  __shared__ __hip_bfloat16 tile[32][33];
  int bkv = blockIdx.z;
  int b = bkv >> 2, kvh = bkv & 3;
  int s0 = blockIdx.x * 32, d0 = blockIdx.y * 32;
  int tx = threadIdx.x, ty = threadIdx.y;  // (32,8)
  for (int i = 0; i < 32; i += 8)
    tile[ty + i][tx] = V[((size_t)(b * S) + s0 + ty + i) * HKV + kvh * 128 + d0 + tx];
  __syncthreads();
  for (int i = 0; i < 32; i += 8)
    Vt[((size_t)bkv * 128 + d0 + ty + i) * S + s0 + tx] = tile[tx][ty + i];
}

// ---------------- bf16 GEMM: C[M,N] = A[M,K] * B[N,K]^T ----------------
template <bool OUT_F32>
__global__ __launch_bounds__(256, 2) void k_gemm_bt(
    const __hip_bfloat16* __restrict__ A, const __hip_bfloat16* __restrict__ B,
    void* __restrict__ Cv, int M, int N, int K) {
  __shared__ __hip_bfloat16 As[128 * 32];
  __shared__ __hip_bfloat16 Bs[128 * 32];
  const int t = threadIdx.x;
  const int w = t >> 6, l = t & 63;
  const int lr = l & 15, lg = l >> 4;
  const int wr = w >> 1, wc = w & 1;
  const int bm = blockIdx.x, bn = blockIdx.y;

  const __hip_bfloat16* ga = A + (size_t)(bm * 128 + (t >> 2)) * K + (t & 3) * 8;
  const __hip_bfloat16* gb = B + (size_t)(bn * 128 + (t >> 2)) * K + (t & 3) * 8;
  __hip_bfloat16* la = As + w * 512;
  __hip_bfloat16* lb = Bs + w * 512;

  f32x4 acc[4][4] = {};

  const int nk = K >> 5;
  for (int kb = 0; kb < nk; ++kb) {
    gl_lds16(ga, la);
    gl_lds16(ga + (size_t)64 * K, la + 2048);
    gl_lds16(gb, lb);
    gl_lds16(gb + (size_t)64 * K, lb + 2048);
    ga += 32; gb += 32;
    asm volatile("s_waitcnt vmcnt(0)" ::: "memory");
    __syncthreads();
    bf16x8 af[4], bfr[4];
#pragma unroll
    for (int m = 0; m < 4; ++m)
      af[m] = *reinterpret_cast<const bf16x8*>(&As[(wr * 64 + m * 16 + lr) * 32 + lg * 8]);
#pragma unroll
    for (int n = 0; n < 4; ++n)
      bfr[n] = *reinterpret_cast<const bf16x8*>(&Bs[(wc * 64 + n * 16 + lr) * 32 + lg * 8]);
#pragma unroll
    for (int m = 0; m < 4; ++m)
#pragma unroll
      for (int n = 0; n < 4; ++n)
        acc[m][n] = __builtin_amdgcn_mfma_f32_16x16x32_bf16(af[m], bfr[n], acc[m][n], 0, 0, 0);
    __syncthreads();
  }

  const int row0 = bm * 128 + wr * 64, col0 = bn * 128 + wc * 64;
#pragma unroll
  for (int m = 0; m < 4; ++m)
#pragma unroll
    for (int n = 0; n < 4; ++n)
#pragma unroll
      for (int r = 0; r < 4; ++r) {
        int row = row0 + m * 16 + lg * 4 + r;
        int col = col0 + n * 16 + lr;
        if (OUT_F32)
          ((float*)Cv)[(size_t)row * N + col] = acc[m][n][r];
        else
          ((__hip_bfloat16*)Cv)[(size_t)row * N + col] = __float2bfloat16(acc[m][n][r]);
      }
}

// ---------------- causal GQA flash attention, LDS-staged double-buffered ----------------
// Q:[B*S][2048] K:[B*S][512] Vt:[(b*4+kvh)*128+d][S] ctx:[B*S][2048]
// 8 waves/block, 128 q-rows/block (16/wave), KVB=64.
__global__ __launch_bounds__(512, 1) void k_attn(
    const __hip_bfloat16* __restrict__ Q, const __hip_bfloat16* __restrict__ Kb,
    const __hip_bfloat16* __restrict__ Vt, __hip_bfloat16* __restrict__ ctx, int S) {
  // K tile: [64 rows][128 cols] bf16, row = 256B = 16 chunks of 16B, chunk XOR-swizzled by (row&7)
  // V tile: [128 d][64 s] bf16, row = 128B = 8 chunks, XOR-swizzled by (d&7)
  __shared__ __hip_bfloat16 Ks[2][64 * 128];
  __shared__ __hip_bfloat16 Vs[2][128 * 64];
  __shared__ __hip_bfloat16 Plds[8][16][72];

  // ---- block swizzle: XCD g owns (b,kvh) group g; heavy qt first ----
  const int bid = blockIdx.x;            // 512 blocks
  const int g  = bid & 7;                // XCD group = b*4+kvh
  const int i2 = bid >> 3;               // 0..63
  const int hi = i2 >> 4;                // head-in-group 0..3
  const int qt = 15 - (i2 & 15);         // reversed: heavy first
  const int b  = g >> 2, kvh = g & 3;
  const int h  = kvh * 4 + hi;

  const int t = threadIdx.x, w = t >> 6, l = t & 63;
  const int lr = l & 15, lg = l >> 4;
  const int q0 = qt * 128 + w * 16;      // wave's q-row base
  const float scale = 0.08838834764831845f;

  const __hip_bfloat16* Qp = Q + ((size_t)(b * S) + q0) * HQ + h * 128;
  bf16x8 aq[4];
#pragma unroll
  for (int kk = 0; kk < 4; ++kk)
    aq[kk] = *reinterpret_cast<const bf16x8*>(&Qp[(size_t)lr * HQ + kk * 32 + lg * 8]);

  const __hip_bfloat16* KG = Kb + (size_t)(b * S) * HKV + kvh * 128;
  const __hip_bfloat16* VG = Vt + ((size_t)(b * NKV + kvh) * 128) * S;

  // staging: per wave 2 K-insts + 2 V-insts of 1KB each
  auto stageK = [&](int buf, int kv0) {
#pragma unroll
    for (int j = 0; j < 2; ++j) {
      int off16 = (w * 2 + j) * 64 + l;          // 16B-chunk idx in tile
      int row = off16 >> 4;                      // 16 chunks/row
      int c_st = off16 & 15;
      int c_nat = c_st ^ (row & 7);
      gl_lds16(KG + (size_t)(kv0 + row) * HKV + c_nat * 8,
               &Ks[buf][(w * 2 + j) * 512]);
    }
  };
  auto stageV = [&](int buf, int kv0) {
#pragma unroll
    for (int j = 0; j < 2; ++j) {
      int off16 = (w * 2 + j) * 64 + l;
      int d = off16 >> 3;                        // 8 chunks/row
      int c_st = off16 & 7;
      int c_nat = c_st ^ (d & 7);
      gl_lds16(VG + (size_t)d * S + kv0 + c_nat * 8,
               &Vs[buf][(w * 2 + j) * 512]);
    }
  };

  f32x4 oacc[8] = {};
  float m_i[4], l_i[4];
#pragma unroll
  for (int r = 0; r < 4; ++r) { m_i[r] = -3.0e38f; l_i[r] = 0.0f; }

  const int nt = 2 * qt + 2;
  stageK(0, 0); stageV(0, 0);
  int cur = 0;
  for (int tkv = 0; tkv < nt; ++tkv) {
    const int kv0 = tkv * KVB;
    if (tkv + 1 < nt) {
      stageK(cur ^ 1, kv0 + KVB);
      stageV(cur ^ 1, kv0 + KVB);
      asm volatile("s_waitcnt vmcnt(4)" ::: "memory");
    } else {
      asm volatile("s_waitcnt vmcnt(0)" ::: "memory");
    }
    __builtin_amdgcn_sched_barrier(0);
    __builtin_amdgcn_s_barrier();

    const bool anymask = (kv0 + KVB - 1) > q0;

    // ---- QK^T ----
    float smax[4];
#pragma unroll
    for (int r = 0; r < 4; ++r) smax[r] = -3.0e38f;
    f32x4 sreg[4];
#pragma unroll
    for (int ks = 0; ks < 4; ++ks) {
      f32x4 s = {0.f, 0.f, 0.f, 0.f};
#pragma unroll
      for (int kk = 0; kk < 4; ++kk) {
        int c = (kk * 4 + lg) ^ (lr & 7);
        bf16x8 kf = *reinterpret_cast<const bf16x8*>(&Ks[cur][(ks * 16 + lr) * 128 + c * 8]);
        s = __builtin_amdgcn_mfma_f32_16x16x32_bf16(aq[kk], kf, s, 0, 0, 0);
      }
      const int kvcol = kv0 + ks * 16 + lr;
#pragma unroll
      for (int r = 0; r < 4; ++r) {
        float v = s[r] * scale;
        if (anymask && kvcol > q0 + lg * 4 + r) v = -1.0e30f;
        s[r] = v;
        smax[r] = fmaxf(smax[r], v);
      }
      sreg[ks] = s;
    }
#pragma unroll
    for (int off = 1; off < 16; off <<= 1)
#pragma unroll
      for (int r = 0; r < 4; ++r) smax[r] = fmaxf(smax[r], __shfl_xor(smax[r], off, 64));

    float fac[4];
#pragma unroll
    for (int r = 0; r < 4; ++r) {
      float mn = fmaxf(m_i[r], smax[r]);
      fac[r] = __expf(m_i[r] - mn);
      m_i[r] = mn;
      l_i[r] *= fac[r];
    }
#pragma unroll
    for (int dt = 0; dt < 8; ++dt)
#pragma unroll
      for (int r = 0; r < 4; ++r) oacc[dt][r] *= fac[r];

    float rs[4] = {0.f, 0.f, 0.f, 0.f};
#pragma unroll
    for (int ks = 0; ks < 4; ++ks)
#pragma unroll
      for (int r = 0; r < 4; ++r) {
        float p = __expf(sreg[ks][r] - m_i[r]);
        rs[r] += p;
        Plds[w][lg * 4 + r][ks * 16 + lr] = __float2bfloat16(p);
      }
#pragma unroll
    for (int off = 1; off < 16; off <<= 1)
#pragma unroll
      for (int r = 0; r < 4; ++r) rs[r] += __shfl_xor(rs[r], off, 64);
#pragma unroll
    for (int r = 0; r < 4; ++r) l_i[r] += rs[r];

    asm volatile("s_waitcnt lgkmcnt(0)" ::: "memory");
    __builtin_amdgcn_sched_barrier(0);

    bf16x8 pa[2];
    pa[0] = *reinterpret_cast<const bf16x8*>(&Plds[w][lr][lg * 8]);
    pa[1] = *reinterpret_cast<const bf16x8*>(&Plds[w][lr][32 + lg * 8]);
#pragma unroll
    for (int dt = 0; dt < 8; ++dt) {
      f32x4 o = oacc[dt];
#pragma unroll
      for (int kk = 0; kk < 2; ++kk) {
        int c = (kk * 4 + lg) ^ (lr & 7);
        bf16x8 vf = *reinterpret_cast<const bf16x8*>(&Vs[cur][(dt * 16 + lr) * 64 + c * 8]);
        o = __builtin_amdgcn_mfma_f32_16x16x32_bf16(pa[kk], vf, o, 0, 0, 0);
      }
      oacc[dt] = o;
    }
    __builtin_amdgcn_s_barrier();
    cur ^= 1;
  }

  float inv_l[4];
#pragma unroll
  for (int r = 0; r < 4; ++r) inv_l[r] = 1.0f / l_i[r];
  __hip_bfloat16* Cp = ctx + ((size_t)(b * S) + q0) * HQ + h * 128;
#pragma unroll
  for (int dt = 0; dt < 8; ++dt)
#pragma unroll
    for (int r = 0; r < 4; ++r)
      Cp[(size_t)(lg * 4 + r) * HQ + dt * 16 + lr] =
          __float2bfloat16(oacc[dt][r] * inv_l[r]);
}

// ---------------------------------------------------------------
extern "C" void kernel_launch(void* const* d_in, const int* in_sizes, int n_in,
                              void* d_out, int out_size, void* d_ws, size_t ws_size,
                              hipStream_t stream) {
  const int B = 2, S = 2048, H = 2048;
  const int M = B * S;  // 4096 tokens

  const float* hs = (const float*)d_in[0];
  const float* wq = (const float*)d_in[1];
  const float* wk = (const float*)d_in[2];
  const float* wv = (const float*)d_in[3];
  const float* wo = (const float*)d_in[4];
  const int* pid = (const int*)d_in[6];

  char* p = (char*)d_ws;
  auto carve = [&](size_t bytes) {
    void* r = (void*)p;
    p += (bytes + 255) & ~(size_t)255;
    return r;
  };
  __hip_bfloat16* Xb  = (__hip_bfloat16*)carve((size_t)M * H * 2);
  __hip_bfloat16* Wqb = (__hip_bfloat16*)carve((size_t)HQ * H * 2);
  __hip_bfloat16* Wkb = (__hip_bfloat16*)carve((size_t)HKV * H * 2);
  __hip_bfloat16* Wvb = (__hip_bfloat16*)carve((size_t)HKV * H * 2);
  __hip_bfloat16* Wob = (__hip_bfloat16*)carve((size_t)H * HQ * 2);
  __hip_bfloat16* Qb  = (__hip_bfloat16*)carve((size_t)M * HQ * 2);
  __hip_bfloat16* Kb  = (__hip_bfloat16*)carve((size_t)M * HKV * 2);
  __hip_bfloat16* Vb  = (__hip_bfloat16*)carve((size_t)M * HKV * 2);
  __hip_bfloat16* Vtb = (__hip_bfloat16*)carve((size_t)M * HKV * 2);
  __hip_bfloat16* Ctx = (__hip_bfloat16*)carve((size_t)M * HQ * 2);
  float* cosT = (float*)carve((size_t)M * 64 * 4);
  float* sinT = (float*)carve((size_t)M * 64 * 4);

  {
    int n4 = M * H / 4;
    k_cast_bf16<<<(n4 + 255) / 256, 256, 0, stream>>>(hs, Xb, n4);
    n4 = HQ * H / 4;
    k_cast_bf16<<<(n4 + 255) / 256, 256, 0, stream>>>(wq, Wqb, n4);
    n4 = HKV * H / 4;
    k_cast_bf16<<<(n4 + 255) / 256, 256, 0, stream>>>(wk, Wkb, n4);
    k_cast_bf16<<<(n4 + 255) / 256, 256, 0, stream>>>(wv, Wvb, n4);
    n4 = H * HQ / 4;
    k_cast_bf16<<<(n4 + 255) / 256, 256, 0, stream>>>(wo, Wob, n4);
  }

  k_rope_table<<<(M * 64 + 255) / 256, 256, 0, stream>>>(pid, cosT, sinT, M);

  k_gemm_bt<false><<<dim3(M / 128, HQ / 128), 256, 0, stream>>>(Xb, Wqb, Qb, M, HQ, H);
  k_gemm_bt<false><<<dim3(M / 128, HKV / 128), 256, 0, stream>>>(Xb, Wkb, Kb, M, HKV, H);
  k_gemm_bt<false><<<dim3(M / 128, HKV / 128), 256, 0, stream>>>(Xb, Wvb, Vb, M, HKV, H);

  k_rope_apply<<<(M * NH * 64 + 255) / 256, 256, 0, stream>>>(Qb, cosT, sinT, NH, M);
  k_rope_apply<<<(M * NKV * 64 + 255) / 256, 256, 0, stream>>>(Kb, cosT, sinT, NKV, M);

  k_transpose_v<<<dim3(S / 32, 128 / 32, B * NKV), dim3(32, 8), 0, stream>>>(Vb, Vtb, S);

  // attention: 512 blocks (16 qt x 32 bh), swizzled
  k_attn<<<dim3(16 * 32), 512, 0, stream>>>(Qb, Kb, Vtb, Ctx, S);

  k_gemm_bt<true><<<dim3(M / 128, H / 128), 256, 0, stream>>>(Ctx, Wob, (float*)d_out, M, H, HQ);
}

// Round 3
// 310.418 us; speedup vs baseline: 2.1454x; 1.1246x over previous
//
#include <hip/hip_runtime.h>
#include <hip/hip_bf16.h>
#include <stdint.h>

typedef __bf16 bf16x8 __attribute__((ext_vector_type(8)));
typedef float f32x4 __attribute__((ext_vector_type(4)));

#define NH 16
#define NKV 4
#define HD 128
#define HQ (NH*HD)    // 2048
#define HKV (NKV*HD)  // 512
#define LDX 3072      // fused QKV row stride
#define KVB 64

__device__ __forceinline__ void gl_lds16(const void* g, void* l) {
  __builtin_amdgcn_global_load_lds(
      (const __attribute__((address_space(1))) void*)g,
      (__attribute__((address_space(3))) void*)l, 16, 0, 0);
}

// ---------------- fp32 -> bf16 cast ----------------
__global__ void k_cast_bf16(const float* __restrict__ in,
                            __hip_bfloat16* __restrict__ out, int n4) {
  int i = blockIdx.x * blockDim.x + threadIdx.x;
  if (i >= n4) return;
  float4 v = reinterpret_cast<const float4*>(in)[i];
  union { __hip_bfloat16 b[4]; ushort4 u; } o;
  o.b[0] = __float2bfloat16(v.x); o.b[1] = __float2bfloat16(v.y);
  o.b[2] = __float2bfloat16(v.z); o.b[3] = __float2bfloat16(v.w);
  reinterpret_cast<ushort4*>(out)[i] = o.u;
}

// ---------------- RoPE cos/sin table ----------------
__global__ void k_rope_table(const int* __restrict__ pid,
                             float* __restrict__ cosT, float* __restrict__ sinT,
                             int ntok) {
  int idx = blockIdx.x * blockDim.x + threadIdx.x;
  if (idx >= ntok * 64) return;
  int tok = idx >> 6, i = idx & 63;
  bool is64 = (pid[1] == 0);
  int pos = is64 ? pid[2 * tok] : pid[tok];
  float f = (float)pos * __expf(-(float)i * (9.210340371976184f / 64.0f));
  cosT[idx] = cosf(f);
  sinT[idx] = sinf(f);
}

// ---------------- RoPE on fused XQKV (heads 0..15 = Q, 16..19 = K) ----------------
__global__ void k_rope_apply2(__hip_bfloat16* __restrict__ X,
                              const float* __restrict__ cosT,
                              const float* __restrict__ sinT, int ntok) {
  int idx = blockIdx.x * blockDim.x + threadIdx.x;
  if (idx >= ntok * 20 * 64) return;
  int i = idx & 63;
  int hh = (idx >> 6) % 20;
  int tok = idx / (20 * 64);
  size_t base = (size_t)tok * LDX + hh * 128;   // Q cols 0..2047, K cols 2048..2559
  float c = cosT[tok * 64 + i], s = sinT[tok * 64 + i];
  float x0 = __bfloat162float(X[base + i]);
  float x1 = __bfloat162float(X[base + 64 + i]);
  X[base + i]      = __float2bfloat16(x0 * c - x1 * s);
  X[base + 64 + i] = __float2bfloat16(x1 * c + x0 * s);
}

// ---------------- V transpose from XQKV cols 2560.. -> [(b*4+kvh)*128+d][s] ----------------
__global__ void k_transpose_v(const __hip_bfloat16* __restrict__ X,
                              __hip_bfloat16* __restrict__ Vt, int S) {
  __shared__ __hip_bfloat16 tile[32][33];
  int bkv = blockIdx.z;
  int b = bkv >> 2, kvh = bkv & 3;
  int s0 = blockIdx.x * 32, d0 = blockIdx.y * 32;
  int tx = threadIdx.x, ty = threadIdx.y;  // (32,8)
  for (int i = 0; i < 32; i += 8)
    tile[ty + i][tx] = X[((size_t)(b * S) + s0 + ty + i) * LDX + 2560 + kvh * 128 + d0 + tx];
  __syncthreads();
  for (int i = 0; i < 32; i += 8)
    Vt[((size_t)bkv * 128 + d0 + ty + i) * S + s0 + tx] = tile[tx][ty + i];
}

// ---------------- 256x256x64 8-phase GEMM: C = A[M,K] * B[N,K]^T ----------------
// MODE 0: fused QKV (B = Wq|Wk|Wv by bn, bf16 out, ld=Nld)
// MODE 1: plain (B = Bq, f32 out, ld=Nld)
// waves 2Mx4N; per-wave C = 128x64; phases per K-tile: (kk0,mh0)(kk0,mh1)(kk1,mh0)(kk1,mh1)
// LDS: K-half-granular [2 dbuf][2 khalf][256][32]; stage order per tile:
//   P0: A-k1(t+1)  P1: B-k1(t+1)  P2: A-k0(t+2)  P3: B-k0(t+2); vmcnt(4) at P3 end.
template <int MODE>
__global__ __launch_bounds__(512, 2) void k_gemm256(
    const __hip_bfloat16* __restrict__ A,
    const __hip_bfloat16* __restrict__ Bq,
    const __hip_bfloat16* __restrict__ Bk,
    const __hip_bfloat16* __restrict__ Bv,
    void* __restrict__ Cv, int Nld, int K, int nbm) {
  __shared__ __hip_bfloat16 As[2][2][256 * 32];
  __shared__ __hip_bfloat16 Bs[2][2][256 * 32];

  const int t = threadIdx.x, w = t >> 6, l = t & 63;
  const int lr = l & 15, lg = l >> 4;
  const int wr = w >> 2, wc = w & 3;

  const int nwg = gridDim.x;
  const int bid = blockIdx.x;
  const int cpx = nwg >> 3;                    // nwg % 8 == 0
  const int id2 = (bid & 7) * cpx + (bid >> 3);
  const int bm = id2 % nbm, bn = id2 / nbm;

  const __hip_bfloat16* Ap = A + (size_t)(bm * 256) * K;
  const __hip_bfloat16* Bp;
  if (MODE == 0) {
    if (bn < 8)       Bp = Bq + (size_t)(bn * 256) * K;
    else if (bn < 10) Bp = Bk + (size_t)((bn - 8) * 256) * K;
    else              Bp = Bv + (size_t)((bn - 10) * 256) * K;
  } else {
    Bp = Bq + (size_t)(bn * 256) * K;
  }

  auto stageHalf = [&](const __hip_bfloat16* gp, __hip_bfloat16* lp, int kt, int kk) {
#pragma unroll
    for (int inst = 0; inst < 2; ++inst) {
      const int chunk = inst * 512 + t;        // 16B chunks; 4 per row of the K-half
      const int row = chunk >> 2, c = chunk & 3;
      gl_lds16(gp + (size_t)row * K + kt * 64 + kk * 32 + c * 8,
               lp + (size_t)(inst * 512 + (w << 6)) * 8);
    }
  };

  f32x4 acc[8][4] = {};
  const int nt = K >> 6;

  // prologue: tile0 complete + tile1 k0
  stageHalf(Ap, As[0][0], 0, 0);
  stageHalf(Bp, Bs[0][0], 0, 0);
  stageHalf(Ap, As[0][1], 0, 1);
  stageHalf(Bp, Bs[0][1], 0, 1);
  stageHalf(Ap, As[1][0], 1, 0);
  stageHalf(Bp, Bs[1][0], 1, 0);
  asm volatile("s_waitcnt vmcnt(4)" ::: "memory");
  __builtin_amdgcn_s_barrier();
  asm volatile("" ::: "memory");

  for (int tt = 0; tt < nt; ++tt) {
    const int cur = tt & 1;
    const int nx1 = (tt + 1 < nt) ? tt + 1 : nt - 1;   // clamp: redundant restage is race-free
    const int nx2 = (tt + 2 < nt) ? tt + 2 : nt - 1;
    bf16x8 bF[4];
#pragma unroll
    for (int ph = 0; ph < 4; ++ph) {
      const int kk = ph >> 1, mh = ph & 1;
      bf16x8 aF[4];
      if (mh == 0) {
#pragma unroll
        for (int n = 0; n < 4; ++n)
          bF[n] = *reinterpret_cast<const bf16x8*>(
              &Bs[cur][kk][(wc * 64 + n * 16 + lr) * 32 + lg * 8]);
      }
#pragma unroll
      for (int m = 0; m < 4; ++m)
        aF[m] = *reinterpret_cast<const bf16x8*>(
            &As[cur][kk][(wr * 128 + mh * 64 + m * 16 + lr) * 32 + lg * 8]);
      if (ph == 0)      stageHalf(Ap, As[nx1 & 1][1], nx1, 1);
      else if (ph == 1) stageHalf(Bp, Bs[nx1 & 1][1], nx1, 1);
      else if (ph == 2) stageHalf(Ap, As[nx2 & 1][0], nx2, 0);
      else              stageHalf(Bp, Bs[nx2 & 1][0], nx2, 0);
      asm volatile("" ::: "memory");
      __builtin_amdgcn_s_barrier();
      asm volatile("" ::: "memory");
      __builtin_amdgcn_s_setprio(1);
#pragma unroll
      for (int m = 0; m < 4; ++m)
#pragma unroll
        for (int n = 0; n < 4; ++n)
          acc[mh * 4 + m][n] = __builtin_amdgcn_mfma_f32_16x16x32_bf16(
              aF[m], bF[n], acc[mh * 4 + m][n], 0, 0, 0);
      __builtin_amdgcn_s_setprio(0);
      if (ph == 3) asm volatile("s_waitcnt vmcnt(4)" ::: "memory");
      asm volatile("" ::: "memory");
      __builtin_amdgcn_s_barrier();
      asm volatile("" ::: "memory");
    }
  }

  const int row0 = bm * 256 + wr * 128;
  const int col0 = bn * 256 + wc * 64;
  if (MODE == 0) {
    __hip_bfloat16* C = (__hip_bfloat16*)Cv;
#pragma unroll
    for (int m = 0; m < 8; ++m)
#pragma unroll
      for (int n = 0; n < 4; ++n)
#pragma unroll
        for (int r = 0; r < 4; ++r)
          C[(size_t)(row0 + m * 16 + lg * 4 + r) * Nld + col0 + n * 16 + lr] =
              __float2bfloat16(acc[m][n][r]);
  } else {
    float* C = (float*)Cv;
#pragma unroll
    for (int m = 0; m < 8; ++m)
#pragma unroll
      for (int n = 0; n < 4; ++n)
#pragma unroll
        for (int r = 0; r < 4; ++r)
          C[(size_t)(row0 + m * 16 + lg * 4 + r) * Nld + col0 + n * 16 + lr] =
              acc[m][n][r];
  }
}

// ---------------- causal GQA flash attention ----------------
// X (fused QKV): Q at col h*128, K at col 2048+kvh*128, row stride LDX.
// Vt:[(b*4+kvh)*128+d][S]  ctx:[B*S][2048]
__global__ __launch_bounds__(512, 4) void k_attn(
    const __hip_bfloat16* __restrict__ X, const __hip_bfloat16* __restrict__ Vt,
    __hip_bfloat16* __restrict__ ctx, int S) {
  __shared__ __hip_bfloat16 Ks[2][64 * 128];    // 16KB x2
  __shared__ __hip_bfloat16 Vs[2][128 * 64];    // 16KB x2
  __shared__ __hip_bfloat16 Plds[8][16][64];    // 16KB, XOR-swizzled chunks

  const int bid = blockIdx.x;            // 512 blocks
  const int g  = bid & 7;                // XCD group = b*4+kvh
  const int i2 = bid >> 3;               // 0..63
  const int hi = i2 >> 4;                // head-in-group 0..3
  const int b16 = i2 & 15;
  const int qt = (b16 & 1) ? (b16 >> 1) : (15 - (b16 >> 1));  // 15,0,14,1,... pairing
  const int b  = g >> 2, kvh = g & 3;
  const int h  = kvh * 4 + hi;

  const int t = threadIdx.x, w = t >> 6, l = t & 63;
  const int lr = l & 15, lg = l >> 4;
  const int q0 = qt * 128 + w * 16;
  const float scale = 0.08838834764831845f;

  const __hip_bfloat16* Qp = X + ((size_t)(b * S) + q0) * LDX + h * 128;
  bf16x8 aq[4];
#pragma unroll
  for (int kk = 0; kk < 4; ++kk)
    aq[kk] = *reinterpret_cast<const bf16x8*>(&Qp[(size_t)lr * LDX + kk * 32 + lg * 8]);

  const __hip_bfloat16* KG = X + (size_t)(b * S) * LDX + 2048 + kvh * 128;
  const __hip_bfloat16* VG = Vt + ((size_t)(b * NKV + kvh) * 128) * S;

  auto stageK = [&](int buf, int kv0) {
#pragma unroll
    for (int j = 0; j < 2; ++j) {
      int off16 = (w * 2 + j) * 64 + l;
      int row = off16 >> 4;
      int c_nat = (off16 & 15) ^ (row & 7);
      gl_lds16(KG + (size_t)(kv0 + row) * LDX + c_nat * 8,
               &Ks[buf][(w * 2 + j) * 512]);
    }
  };
  auto stageV = [&](int buf, int kv0) {
#pragma unroll
    for (int j = 0; j < 2; ++j) {
      int off16 = (w * 2 + j) * 64 + l;
      int d = off16 >> 3;
      int c_nat = (off16 & 7) ^ (d & 7);
      gl_lds16(VG + (size_t)d * S + kv0 + c_nat * 8,
               &Vs[buf][(w * 2 + j) * 512]);
    }
  };

  f32x4 oacc[8] = {};
  float m_i[4], l_i[4];
#pragma unroll
  for (int r = 0; r < 4; ++r) { m_i[r] = -3.0e38f; l_i[r] = 0.0f; }

  const int nt = 2 * qt + 2;
  stageK(0, 0); stageV(0, 0);
  int cur = 0;
  for (int tkv = 0; tkv < nt; ++tkv) {
    const int kv0 = tkv * KVB;
    if (tkv + 1 < nt) {
      stageK(cur ^ 1, kv0 + KVB);
      stageV(cur ^ 1, kv0 + KVB);
      asm volatile("s_waitcnt vmcnt(4)" ::: "memory");
    } else {
      asm volatile("s_waitcnt vmcnt(0)" ::: "memory");
    }
    __builtin_amdgcn_sched_barrier(0);
    __builtin_amdgcn_s_barrier();
    asm volatile("" ::: "memory");

    const bool anymask = (kv0 + KVB - 1) > q0;

    // ---- QK^T ----
    float smax[4];
#pragma unroll
    for (int r = 0; r < 4; ++r) smax[r] = -3.0e38f;
    f32x4 sreg[4];
    __builtin_amdgcn_s_setprio(1);
#pragma unroll
    for (int ks = 0; ks < 4; ++ks) {
      f32x4 s = {0.f, 0.f, 0.f, 0.f};
#pragma unroll
      for (int kk = 0; kk < 4; ++kk) {
        int c = (kk * 4 + lg) ^ (lr & 7);
        bf16x8 kf = *reinterpret_cast<const bf16x8*>(&Ks[cur][(ks * 16 + lr) * 128 + c * 8]);
        s = __builtin_amdgcn_mfma_f32_16x16x32_bf16(aq[kk], kf, s, 0, 0, 0);
      }
      const int kvcol = kv0 + ks * 16 + lr;
#pragma unroll
      for (int r = 0; r < 4; ++r) {
        float v = s[r] * scale;
        if (anymask && kvcol > q0 + lg * 4 + r) v = -1.0e30f;
        s[r] = v;
        smax[r] = fmaxf(smax[r], v);
      }
      sreg[ks] = s;
    }
    __builtin_amdgcn_s_setprio(0);
#pragma unroll
    for (int off = 1; off < 16; off <<= 1)
#pragma unroll
      for (int r = 0; r < 4; ++r) smax[r] = fmaxf(smax[r], __shfl_xor(smax[r], off, 64));

    // defer-max (T13): skip O/l rescale when max growth <= 8
    float mx[4]; bool okd = true;
#pragma unroll
    for (int r = 0; r < 4; ++r) {
      mx[r] = fmaxf(m_i[r], smax[r]);
      okd = okd && (smax[r] - m_i[r] <= 8.0f);
    }
    if (!__all(okd)) {
#pragma unroll
      for (int r = 0; r < 4; ++r) {
        float fac = __expf(m_i[r] - mx[r]);
        m_i[r] = mx[r];
        l_i[r] *= fac;
#pragma unroll
        for (int dt = 0; dt < 8; ++dt) oacc[dt][r] *= fac;
      }
    }

    float rs[4] = {0.f, 0.f, 0.f, 0.f};
#pragma unroll
    for (int ks = 0; ks < 4; ++ks)
#pragma unroll
      for (int r = 0; r < 4; ++r) {
        float p = __expf(sreg[ks][r] - m_i[r]);
        rs[r] += p;
        int row = lg * 4 + r;
        int cst = ((ks * 2 + (lr >> 3)) ^ (row & 7));
        Plds[w][row][cst * 8 + (lr & 7)] = __float2bfloat16(p);
      }
#pragma unroll
    for (int off = 1; off < 16; off <<= 1)
#pragma unroll
      for (int r = 0; r < 4; ++r) rs[r] += __shfl_xor(rs[r], off, 64);
#pragma unroll
    for (int r = 0; r < 4; ++r) l_i[r] += rs[r];

    asm volatile("s_waitcnt lgkmcnt(0)" ::: "memory");
    __builtin_amdgcn_sched_barrier(0);

    bf16x8 pa[2];
    pa[0] = *reinterpret_cast<const bf16x8*>(&Plds[w][lr][((0 + lg) ^ (lr & 7)) * 8]);
    pa[1] = *reinterpret_cast<const bf16x8*>(&Plds[w][lr][((4 + lg) ^ (lr & 7)) * 8]);
    __builtin_amdgcn_s_setprio(1);
#pragma unroll
    for (int dt = 0; dt < 8; ++dt) {
      f32x4 o = oacc[dt];
#pragma unroll
      for (int kk = 0; kk < 2; ++kk) {
        int c = (kk * 4 + lg) ^ (lr & 7);
        bf16x8 vf = *reinterpret_cast<const bf16x8*>(&Vs[cur][(dt * 16 + lr) * 64 + c * 8]);
        o = __builtin_amdgcn_mfma_f32_16x16x32_bf16(pa[kk], vf, o, 0, 0, 0);
      }
      oacc[dt] = o;
    }
    __builtin_amdgcn_s_setprio(0);
    asm volatile("" ::: "memory");
    __builtin_amdgcn_s_barrier();
    asm volatile("" ::: "memory");
    cur ^= 1;
  }

  float inv_l[4];
#pragma unroll
  for (int r = 0; r < 4; ++r) inv_l[r] = 1.0f / l_i[r];
  __hip_bfloat16* Cp = ctx + ((size_t)(b * S) + q0) * HQ + h * 128;
#pragma unroll
  for (int dt = 0; dt < 8; ++dt)
#pragma unroll
    for (int r = 0; r < 4; ++r)
      Cp[(size_t)(lg * 4 + r) * HQ + dt * 16 + lr] =
          __float2bfloat16(oacc[dt][r] * inv_l[r]);
}

// ---------------------------------------------------------------
extern "C" void kernel_launch(void* const* d_in, const int* in_sizes, int n_in,
                              void* d_out, int out_size, void* d_ws, size_t ws_size,
                              hipStream_t stream) {
  const int B = 2, S = 2048, H = 2048;
  const int M = B * S;  // 4096 tokens

  const float* hs = (const float*)d_in[0];
  const float* wq = (const float*)d_in[1];
  const float* wk = (const float*)d_in[2];
  const float* wv = (const float*)d_in[3];
  const float* wo = (const float*)d_in[4];
  const int* pid = (const int*)d_in[6];

  char* p = (char*)d_ws;
  auto carve = [&](size_t bytes) {
    void* r = (void*)p;
    p += (bytes + 255) & ~(size_t)255;
    return r;
  };
  __hip_bfloat16* Xb   = (__hip_bfloat16*)carve((size_t)M * H * 2);
  __hip_bfloat16* Wqb  = (__hip_bfloat16*)carve((size_t)HQ * H * 2);
  __hip_bfloat16* Wkb  = (__hip_bfloat16*)carve((size_t)HKV * H * 2);
  __hip_bfloat16* Wvb  = (__hip_bfloat16*)carve((size_t)HKV * H * 2);
  __hip_bfloat16* Wob  = (__hip_bfloat16*)carve((size_t)H * HQ * 2);
  __hip_bfloat16* XQKV = (__hip_bfloat16*)carve((size_t)M * LDX * 2);
  __hip_bfloat16* Vtb  = (__hip_bfloat16*)carve((size_t)M * HKV * 2);
  __hip_bfloat16* Ctx  = (__hip_bfloat16*)carve((size_t)M * HQ * 2);
  float* cosT = (float*)carve((size_t)M * 64 * 4);
  float* sinT = (float*)carve((size_t)M * 64 * 4);

  {
    int n4 = M * H / 4;
    k_cast_bf16<<<(n4 + 255) / 256, 256, 0, stream>>>(hs, Xb, n4);
    n4 = HQ * H / 4;
    k_cast_bf16<<<(n4 + 255) / 256, 256, 0, stream>>>(wq, Wqb, n4);
    n4 = HKV * H / 4;
    k_cast_bf16<<<(n4 + 255) / 256, 256, 0, stream>>>(wk, Wkb, n4);
    k_cast_bf16<<<(n4 + 255) / 256, 256, 0, stream>>>(wv, Wvb, n4);
    n4 = H * HQ / 4;
    k_cast_bf16<<<(n4 + 255) / 256, 256, 0, stream>>>(wo, Wob, n4);
  }

  k_rope_table<<<(M * 64 + 255) / 256, 256, 0, stream>>>(pid, cosT, sinT, M);

  // fused QKV projection: [M,3072] = Xb[M,2048] * [Wq;Wk;Wv]^T  (192 blocks)
  k_gemm256<0><<<dim3(16 * 12), 512, 0, stream>>>(Xb, Wqb, Wkb, Wvb, XQKV, LDX, H, 16);

  // RoPE on Q heads + K heads (contiguous cols 0..2559)
  k_rope_apply2<<<(M * 20 * 64 + 255) / 256, 256, 0, stream>>>(XQKV, cosT, sinT, M);

  k_transpose_v<<<dim3(S / 32, 128 / 32, B * NKV), dim3(32, 8), 0, stream>>>(XQKV, Vtb, S);

  // attention: 512 blocks (8 xcd-groups x 4 heads x 16 qt), 2 blocks/CU
  k_attn<<<dim3(512), 512, 0, stream>>>(XQKV, Vtb, Ctx, S);

  // output projection (f32 out, 128 blocks)
  k_gemm256<1><<<dim3(16 * 8), 512, 0, stream>>>(Ctx, Wob, nullptr, nullptr,
                                                 (float*)d_out, H, HQ, 16);
}

// Round 4
// 285.496 us; speedup vs baseline: 2.3327x; 1.0873x over previous
//
#include <hip/hip_runtime.h>
#include <hip/hip_bf16.h>
#include <stdint.h>

typedef __bf16 bf16x8 __attribute__((ext_vector_type(8)));
typedef float f32x4 __attribute__((ext_vector_type(4)));
typedef float f32x16 __attribute__((ext_vector_type(16)));

#define NH 16
#define NKV 4
#define HD 128
#define HQ (NH*HD)    // 2048
#define HKV (NKV*HD)  // 512
#define LDX 3072      // fused QKV row stride
#define KVB 64

__device__ __forceinline__ void gl_lds16(const void* g, void* l) {
  __builtin_amdgcn_global_load_lds(
      (const __attribute__((address_space(1))) void*)g,
      (__attribute__((address_space(3))) void*)l, 16, 0, 0);
}

__device__ __forceinline__ uint32_t pk2(float lo, float hi) {
  union { __hip_bfloat16 h[2]; uint32_t u; } x;
  x.h[0] = __float2bfloat16(lo);
  x.h[1] = __float2bfloat16(hi);
  return x.u;
}

// ---------------- fp32 -> bf16 cast ----------------
__global__ void k_cast_bf16(const float* __restrict__ in,
                            __hip_bfloat16* __restrict__ out, int n4) {
  int i = blockIdx.x * blockDim.x + threadIdx.x;
  if (i >= n4) return;
  float4 v = reinterpret_cast<const float4*>(in)[i];
  union { __hip_bfloat16 b[4]; ushort4 u; } o;
  o.b[0] = __float2bfloat16(v.x); o.b[1] = __float2bfloat16(v.y);
  o.b[2] = __float2bfloat16(v.z); o.b[3] = __float2bfloat16(v.w);
  reinterpret_cast<ushort4*>(out)[i] = o.u;
}

// ---------------- RoPE cos/sin table ----------------
__global__ void k_rope_table(const int* __restrict__ pid,
                             float* __restrict__ cosT, float* __restrict__ sinT,
                             int ntok) {
  int idx = blockIdx.x * blockDim.x + threadIdx.x;
  if (idx >= ntok * 64) return;
  int tok = idx >> 6, i = idx & 63;
  bool is64 = (pid[1] == 0);
  int pos = is64 ? pid[2 * tok] : pid[tok];
  float f = (float)pos * __expf(-(float)i * (9.210340371976184f / 64.0f));
  cosT[idx] = cosf(f);
  sinT[idx] = sinf(f);
}

// ---------------- RoPE on fused XQKV (heads 0..15 = Q, 16..19 = K) ----------------
__global__ void k_rope_apply2(__hip_bfloat16* __restrict__ X,
                              const float* __restrict__ cosT,
                              const float* __restrict__ sinT, int ntok) {
  int idx = blockIdx.x * blockDim.x + threadIdx.x;
  if (idx >= ntok * 20 * 64) return;
  int i = idx & 63;
  int hh = (idx >> 6) % 20;
  int tok = idx / (20 * 64);
  size_t base = (size_t)tok * LDX + hh * 128;
  float c = cosT[tok * 64 + i], s = sinT[tok * 64 + i];
  float x0 = __bfloat162float(X[base + i]);
  float x1 = __bfloat162float(X[base + 64 + i]);
  X[base + i]      = __float2bfloat16(x0 * c - x1 * s);
  X[base + 64 + i] = __float2bfloat16(x1 * c + x0 * s);
}

// ---------------- V transpose from XQKV cols 2560.. -> [(b*4+kvh)*128+d][s] ----------------
__global__ void k_transpose_v(const __hip_bfloat16* __restrict__ X,
                              __hip_bfloat16* __restrict__ Vt, int S) {
  __shared__ __hip_bfloat16 tile[32][33];
  int bkv = blockIdx.z;
  int b = bkv >> 2, kvh = bkv & 3;
  int s0 = blockIdx.x * 32, d0 = blockIdx.y * 32;
  int tx = threadIdx.x, ty = threadIdx.y;  // (32,8)
  for (int i = 0; i < 32; i += 8)
    tile[ty + i][tx] = X[((size_t)(b * S) + s0 + ty + i) * LDX + 2560 + kvh * 128 + d0 + tx];
  __syncthreads();
  for (int i = 0; i < 32; i += 8)
    Vt[((size_t)bkv * 128 + d0 + ty + i) * S + s0 + tx] = tile[tx][ty + i];
}

// ---------------- 256x256x64 8-phase GEMM: C = A[M,K] * B[N,K]^T ----------------
template <int MODE>
__global__ __launch_bounds__(512, 2) void k_gemm256(
    const __hip_bfloat16* __restrict__ A,
    const __hip_bfloat16* __restrict__ Bq,
    const __hip_bfloat16* __restrict__ Bk,
    const __hip_bfloat16* __restrict__ Bv,
    void* __restrict__ Cv, int Nld, int K, int nbm) {
  __shared__ __hip_bfloat16 As[2][2][256 * 32];
  __shared__ __hip_bfloat16 Bs[2][2][256 * 32];

  const int t = threadIdx.x, w = t >> 6, l = t & 63;
  const int lr = l & 15, lg = l >> 4;
  const int wr = w >> 2, wc = w & 3;

  const int nwg = gridDim.x;
  const int bid = blockIdx.x;
  const int cpx = nwg >> 3;
  const int id2 = (bid & 7) * cpx + (bid >> 3);
  const int bm = id2 % nbm, bn = id2 / nbm;

  const __hip_bfloat16* Ap = A + (size_t)(bm * 256) * K;
  const __hip_bfloat16* Bp;
  if (MODE == 0) {
    if (bn < 8)       Bp = Bq + (size_t)(bn * 256) * K;
    else if (bn < 10) Bp = Bk + (size_t)((bn - 8) * 256) * K;
    else              Bp = Bv + (size_t)((bn - 10) * 256) * K;
  } else {
    Bp = Bq + (size_t)(bn * 256) * K;
  }

  auto stageHalf = [&](const __hip_bfloat16* gp, __hip_bfloat16* lp, int kt, int kk) {
#pragma unroll
    for (int inst = 0; inst < 2; ++inst) {
      const int chunk = inst * 512 + t;
      const int row = chunk >> 2, c = chunk & 3;
      gl_lds16(gp + (size_t)row * K + kt * 64 + kk * 32 + c * 8,
               lp + (size_t)(inst * 512 + (w << 6)) * 8);
    }
  };

  f32x4 acc[8][4] = {};
  const int nt = K >> 6;

  stageHalf(Ap, As[0][0], 0, 0);
  stageHalf(Bp, Bs[0][0], 0, 0);
  stageHalf(Ap, As[0][1], 0, 1);
  stageHalf(Bp, Bs[0][1], 0, 1);
  stageHalf(Ap, As[1][0], 1, 0);
  stageHalf(Bp, Bs[1][0], 1, 0);
  asm volatile("s_waitcnt vmcnt(4)" ::: "memory");
  __builtin_amdgcn_s_barrier();
  asm volatile("" ::: "memory");

  for (int tt = 0; tt < nt; ++tt) {
    const int cur = tt & 1;
    const int nx1 = (tt + 1 < nt) ? tt + 1 : nt - 1;
    const int nx2 = (tt + 2 < nt) ? tt + 2 : nt - 1;
    bf16x8 bF[4];
#pragma unroll
    for (int ph = 0; ph < 4; ++ph) {
      const int kk = ph >> 1, mh = ph & 1;
      bf16x8 aF[4];
      if (mh == 0) {
#pragma unroll
        for (int n = 0; n < 4; ++n)
          bF[n] = *reinterpret_cast<const bf16x8*>(
              &Bs[cur][kk][(wc * 64 + n * 16 + lr) * 32 + lg * 8]);
      }
#pragma unroll
      for (int m = 0; m < 4; ++m)
        aF[m] = *reinterpret_cast<const bf16x8*>(
            &As[cur][kk][(wr * 128 + mh * 64 + m * 16 + lr) * 32 + lg * 8]);
      if (ph == 0)      stageHalf(Ap, As[nx1 & 1][1], nx1, 1);
      else if (ph == 1) stageHalf(Bp, Bs[nx1 & 1][1], nx1, 1);
      else if (ph == 2) stageHalf(Ap, As[nx2 & 1][0], nx2, 0);
      else              stageHalf(Bp, Bs[nx2 & 1][0], nx2, 0);
      asm volatile("" ::: "memory");
      __builtin_amdgcn_s_barrier();
      asm volatile("" ::: "memory");
      __builtin_amdgcn_s_setprio(1);
#pragma unroll
      for (int m = 0; m < 4; ++m)
#pragma unroll
        for (int n = 0; n < 4; ++n)
          acc[mh * 4 + m][n] = __builtin_amdgcn_mfma_f32_16x16x32_bf16(
              aF[m], bF[n], acc[mh * 4 + m][n], 0, 0, 0);
      __builtin_amdgcn_s_setprio(0);
      if (ph == 3) asm volatile("s_waitcnt vmcnt(4)" ::: "memory");
      asm volatile("" ::: "memory");
      __builtin_amdgcn_s_barrier();
      asm volatile("" ::: "memory");
    }
  }

  const int row0 = bm * 256 + wr * 128;
  const int col0 = bn * 256 + wc * 64;
  if (MODE == 0) {
    __hip_bfloat16* C = (__hip_bfloat16*)Cv;
#pragma unroll
    for (int m = 0; m < 8; ++m)
#pragma unroll
      for (int n = 0; n < 4; ++n)
#pragma unroll
        for (int r = 0; r < 4; ++r)
          C[(size_t)(row0 + m * 16 + lg * 4 + r) * Nld + col0 + n * 16 + lr] =
              __float2bfloat16(acc[m][n][r]);
  } else {
    float* C = (float*)Cv;
#pragma unroll
    for (int m = 0; m < 8; ++m)
#pragma unroll
      for (int n = 0; n < 4; ++n)
#pragma unroll
        for (int r = 0; r < 4; ++r)
          C[(size_t)(row0 + m * 16 + lg * 4 + r) * Nld + col0 + n * 16 + lr] =
              acc[m][n][r];
  }
}

// ---------------- causal GQA flash attention, swapped-operand 32x32 ----------------
// X (fused QKV): Q at col h*128, K at col 2048+kvh*128, row stride LDX.
// Vt:[(b*4+kvh)*128+d][S]  ctx:[B*S][2048]
// 4 waves/block, 32 q-rows/wave (128/block), KVB=64, double-buffered LDS (64KB).
// QK^T = mfma32x32(K,Q): lane owns q-col = l&31; kv spread over regs -> in-register softmax.
__global__ __launch_bounds__(256, 2) void k_attn(
    const __hip_bfloat16* __restrict__ X, const __hip_bfloat16* __restrict__ Vt,
    __hip_bfloat16* __restrict__ ctx, int S) {
  __shared__ __hip_bfloat16 SM[32768];  // Ks[2][64*128] | Vs[2][128*64]

  const int bid = blockIdx.x;            // 512 blocks
  const int g  = bid & 7;                // XCD group = b*4+kvh
  const int i2 = bid >> 3;
  const int hi = i2 >> 4;
  const int b16 = i2 & 15;
  const int qt = (b16 & 1) ? (b16 >> 1) : (15 - (b16 >> 1));
  const int b  = g >> 2, kvh = g & 3;
  const int h  = kvh * 4 + hi;

  const int t = threadIdx.x, w = t >> 6, l = t & 63;
  const int q = l & 31, hf = l >> 5;
  const int q0w = qt * 128 + w * 32;
  const float c1 = 0.12752511f;          // (1/sqrt(128)) * log2(e)

  // Q fragment (B-operand): lane holds Q[q0w+q][m*16 + hf*8 + 0..7]
  const __hip_bfloat16* Qp = X + ((size_t)(b * S) + q0w + q) * LDX + h * 128 + hf * 8;
  bf16x8 aq[8];
#pragma unroll
  for (int m = 0; m < 8; ++m)
    aq[m] = *reinterpret_cast<const bf16x8*>(Qp + m * 16);

  const __hip_bfloat16* KG = X + (size_t)(b * S) * LDX + 2048 + kvh * 128;
  const __hip_bfloat16* VG = Vt + ((size_t)(b * NKV + kvh) * 128) * S;

  auto stageK = [&](int buf, int kv0) {
#pragma unroll
    for (int j = 0; j < 4; ++j) {
      int off16 = (w * 4 + j) * 64 + l;
      int row = off16 >> 4;
      int c_nat = (off16 & 15) ^ (row & 7);
      gl_lds16(KG + (size_t)(kv0 + row) * LDX + c_nat * 8,
               &SM[(size_t)buf * 8192 + (w * 4 + j) * 512]);
    }
  };
  auto stageV = [&](int buf, int kv0) {
#pragma unroll
    for (int j = 0; j < 4; ++j) {
      int off16 = (w * 4 + j) * 64 + l;
      int d = off16 >> 3;
      int c_nat = (off16 & 7) ^ (d & 7);
      gl_lds16(VG + (size_t)d * S + kv0 + c_nat * 8,
               &SM[16384 + (size_t)buf * 8192 + (w * 4 + j) * 512]);
    }
  };

  f32x16 O[4] = {};                      // O^T: lane q-col, d rows
  float m_i = -3.0e38f, l_i = 0.0f;

  const int nt = 2 * qt + 2;
  stageK(0, 0); stageV(0, 0);
  int cur = 0;
  for (int tkv = 0; tkv < nt; ++tkv) {
    const int kv0 = tkv * KVB;
    if (tkv + 1 < nt) {
      stageK(cur ^ 1, kv0 + KVB);
      stageV(cur ^ 1, kv0 + KVB);
      asm volatile("s_waitcnt vmcnt(8)" ::: "memory");
    } else {
      asm volatile("s_waitcnt vmcnt(0)" ::: "memory");
    }
    __builtin_amdgcn_sched_barrier(0);
    __builtin_amdgcn_s_barrier();
    asm volatile("" ::: "memory");

    if (kv0 <= q0w + 31) {               // wave-level skip of fully-masked tiles
      const __hip_bfloat16* Ksb = &SM[(size_t)cur * 8192];
      const __hip_bfloat16* Vsb = &SM[16384 + (size_t)cur * 8192];

      // ---- QK^T: two 32x32 subtiles ----
      f32x16 p[2];
      __builtin_amdgcn_s_setprio(1);
#pragma unroll
      for (int sb = 0; sb < 2; ++sb) {
        f32x16 s = {};
#pragma unroll
        for (int mm = 0; mm < 8; ++mm) {
          int arow = sb * 32 + q;
          int c_lds = (2 * mm + hf) ^ (arow & 7);
          bf16x8 kf = *reinterpret_cast<const bf16x8*>(&Ksb[arow * 128 + c_lds * 8]);
          s = __builtin_amdgcn_mfma_f32_32x32x16_bf16(kf, aq[mm], s, 0, 0, 0);
        }
        p[sb] = s;
      }
      __builtin_amdgcn_s_setprio(0);

      if (kv0 + 63 > q0w) {              // diagonal tile: mask
#pragma unroll
        for (int sb = 0; sb < 2; ++sb)
#pragma unroll
          for (int r = 0; r < 16; ++r) {
            int kv_abs = kv0 + sb * 32 + (r & 3) + 8 * (r >> 2) + 4 * hf;
            if (kv_abs > q0w + q) p[sb][r] = -3.0e38f;
          }
      }

      // ---- in-register softmax (lane owns one q row) ----
      float smax = -3.0e38f;
#pragma unroll
      for (int sb = 0; sb < 2; ++sb)
#pragma unroll
        for (int r = 0; r < 16; ++r) smax = fmaxf(smax, p[sb][r]);
      smax = fmaxf(smax, __shfl_xor(smax, 32, 64));
      float mn = fmaxf(m_i, smax);
      if (__any(smax > m_i + 62.0f)) {   // defer-max: raw-domain THR (~8 scaled)
        float fac = exp2f((m_i - mn) * c1);
        l_i *= fac;
#pragma unroll
        for (int db = 0; db < 4; ++db)
#pragma unroll
          for (int r = 0; r < 16; ++r) O[db][r] *= fac;
        m_i = mn;
      }
      float rs = 0.0f;
#pragma unroll
      for (int sb = 0; sb < 2; ++sb)
#pragma unroll
        for (int r = 0; r < 16; ++r) {
          float e = exp2f((p[sb][r] - m_i) * c1);
          p[sb][r] = e;
          rs += e;
        }
      rs += __shfl_xor(rs, 32, 64);
      l_i += rs;

      // ---- pack P -> bf16, build PV B-fragments via lane^32 exchange ----
      uint32_t pku[2][8], swu[2][8];
#pragma unroll
      for (int sb = 0; sb < 2; ++sb)
#pragma unroll
        for (int gp = 0; gp < 4; ++gp) {
          pku[sb][gp * 2 + 0] = pk2(p[sb][gp * 4 + 0], p[sb][gp * 4 + 1]);
          pku[sb][gp * 2 + 1] = pk2(p[sb][gp * 4 + 2], p[sb][gp * 4 + 3]);
        }
#pragma unroll
      for (int sb = 0; sb < 2; ++sb)
#pragma unroll
        for (int ii = 0; ii < 8; ++ii)
          swu[sb][ii] = __shfl_xor((int)pku[sb][ii], 32, 64);

      // ---- PV: O^T += Vt * P ----
      __builtin_amdgcn_s_setprio(1);
#pragma unroll
      for (int kk = 0; kk < 4; ++kk) {
        const int sb = kk >> 1, bs = (kk & 1) * 4;
        union { uint32_t u[4]; bf16x8 v; } pf;
        pf.u[0] = hf ? swu[sb][bs + 2] : pku[sb][bs + 0];
        pf.u[1] = hf ? swu[sb][bs + 3] : pku[sb][bs + 1];
        pf.u[2] = hf ? pku[sb][bs + 2] : swu[sb][bs + 0];
        pf.u[3] = hf ? pku[sb][bs + 3] : swu[sb][bs + 1];
#pragma unroll
        for (int db = 0; db < 4; ++db) {
          int vrow = db * 32 + q;
          int c_lds = (2 * kk + hf) ^ (vrow & 7);
          bf16x8 vf = *reinterpret_cast<const bf16x8*>(&Vsb[vrow * 64 + c_lds * 8]);
          O[db] = __builtin_amdgcn_mfma_f32_32x32x16_bf16(vf, pf.v, O[db], 0, 0, 0);
        }
      }
      __builtin_amdgcn_s_setprio(0);
    }
    asm volatile("" ::: "memory");
    __builtin_amdgcn_s_barrier();
    asm volatile("" ::: "memory");
    cur ^= 1;
  }

  // ---- epilogue: O^T -> LDS transpose -> coalesced ctx write ----
  float inv = 1.0f / l_i;
  __hip_bfloat16* Lo = &SM[(size_t)w * (32 * 136)];
#pragma unroll
  for (int db = 0; db < 4; ++db)
#pragma unroll
    for (int rr = 0; rr < 4; ++rr) {
      int d0 = db * 32 + rr * 8 + hf * 4;
      uint32_t u0 = pk2(O[db][rr * 4 + 0] * inv, O[db][rr * 4 + 1] * inv);
      uint32_t u1 = pk2(O[db][rr * 4 + 2] * inv, O[db][rr * 4 + 3] * inv);
      *reinterpret_cast<uint2*>(&Lo[q * 136 + d0]) = make_uint2(u0, u1);
    }
  __syncthreads();
  const int rbase = l >> 4, c = l & 15;
#pragma unroll
  for (int it = 0; it < 8; ++it) {
    int row = it * 4 + rbase;
    bf16x8 vv = *reinterpret_cast<const bf16x8*>(&Lo[row * 136 + c * 8]);
    *reinterpret_cast<bf16x8*>(
        &ctx[((size_t)(b * S) + q0w + row) * HQ + h * 128 + c * 8]) = vv;
  }
}

// ---------------------------------------------------------------
extern "C" void kernel_launch(void* const* d_in, const int* in_sizes, int n_in,
                              void* d_out, int out_size, void* d_ws, size_t ws_size,
                              hipStream_t stream) {
  const int B = 2, S = 2048, H = 2048;
  const int M = B * S;  // 4096 tokens

  const float* hs = (const float*)d_in[0];
  const float* wq = (const float*)d_in[1];
  const float* wk = (const float*)d_in[2];
  const float* wv = (const float*)d_in[3];
  const float* wo = (const float*)d_in[4];
  const int* pid = (const int*)d_in[6];

  char* p = (char*)d_ws;
  auto carve = [&](size_t bytes) {
    void* r = (void*)p;
    p += (bytes + 255) & ~(size_t)255;
    return r;
  };
  __hip_bfloat16* Xb   = (__hip_bfloat16*)carve((size_t)M * H * 2);
  __hip_bfloat16* Wqb  = (__hip_bfloat16*)carve((size_t)HQ * H * 2);
  __hip_bfloat16* Wkb  = (__hip_bfloat16*)carve((size_t)HKV * H * 2);
  __hip_bfloat16* Wvb  = (__hip_bfloat16*)carve((size_t)HKV * H * 2);
  __hip_bfloat16* Wob  = (__hip_bfloat16*)carve((size_t)H * HQ * 2);
  __hip_bfloat16* XQKV = (__hip_bfloat16*)carve((size_t)M * LDX * 2);
  __hip_bfloat16* Vtb  = (__hip_bfloat16*)carve((size_t)M * HKV * 2);
  __hip_bfloat16* Ctx  = (__hip_bfloat16*)carve((size_t)M * HQ * 2);
  float* cosT = (float*)carve((size_t)M * 64 * 4);
  float* sinT = (float*)carve((size_t)M * 64 * 4);

  {
    int n4 = M * H / 4;
    k_cast_bf16<<<(n4 + 255) / 256, 256, 0, stream>>>(hs, Xb, n4);
    n4 = HQ * H / 4;
    k_cast_bf16<<<(n4 + 255) / 256, 256, 0, stream>>>(wq, Wqb, n4);
    n4 = HKV * H / 4;
    k_cast_bf16<<<(n4 + 255) / 256, 256, 0, stream>>>(wk, Wkb, n4);
    k_cast_bf16<<<(n4 + 255) / 256, 256, 0, stream>>>(wv, Wvb, n4);
    n4 = H * HQ / 4;
    k_cast_bf16<<<(n4 + 255) / 256, 256, 0, stream>>>(wo, Wob, n4);
  }

  k_rope_table<<<(M * 64 + 255) / 256, 256, 0, stream>>>(pid, cosT, sinT, M);

  // fused QKV projection: [M,3072] = Xb[M,2048] * [Wq;Wk;Wv]^T
  k_gemm256<0><<<dim3(16 * 12), 512, 0, stream>>>(Xb, Wqb, Wkb, Wvb, XQKV, LDX, H, 16);

  k_rope_apply2<<<(M * 20 * 64 + 255) / 256, 256, 0, stream>>>(XQKV, cosT, sinT, M);

  k_transpose_v<<<dim3(S / 32, 128 / 32, B * NKV), dim3(32, 8), 0, stream>>>(XQKV, Vtb, S);

  // attention: 512 blocks (8 xcd-groups x 4 heads x 16 qt), 256 thr, 2 blocks/CU
  k_attn<<<dim3(512), 256, 0, stream>>>(XQKV, Vtb, Ctx, S);

  // output projection (f32 out)
  k_gemm256<1><<<dim3(16 * 8), 512, 0, stream>>>(Ctx, Wob, nullptr, nullptr,
                                                 (float*)d_out, H, HQ, 16);
}